// Round 1
// baseline (170.886 us; speedup 1.0000x reference)
//
#include <hip/hip_runtime.h>
#include <hip/hip_bf16.h>

#define B_ 4
#define C_IN 128
#define C_OUT 256
#define N_IN 40962
#define N_OUT 10242
#define EPS_ 1e-5f

typedef __attribute__((ext_vector_type(8))) short bf16x8;
typedef __attribute__((ext_vector_type(4))) float f32x4;

__device__ __forceinline__ float bf2f(unsigned short u) {
    union { unsigned int i; float f; } c;
    c.i = ((unsigned int)u) << 16;
    return c.f;
}
__device__ __forceinline__ unsigned short f2bf(float f) {
    union { float f; unsigned int i; } c;
    c.f = f;
    unsigned int r = c.i + 0x7FFFu + ((c.i >> 16) & 1u);  // RNE
    return (unsigned short)(r >> 16);
}

// ---------------------------------------------------------------------------
// K1: transpose x[b][k][i] (f32) -> xT[b][i][k] (bf16), coalesced both sides
// ---------------------------------------------------------------------------
#define IBLK 64
#define NB_I ((N_IN + IBLK - 1) / IBLK)  // 641

__global__ __launch_bounds__(256) void k_transpose(const float* __restrict__ x,
                                                   unsigned short* __restrict__ xT) {
    __shared__ float tile[IBLK][C_IN + 1];  // stride 129: (i + k) % 32 banks -> conflict-free writes
    int b  = blockIdx.x / NB_I;
    int ib = blockIdx.x % NB_I;
    int i0 = ib * IBLK;
    int t = threadIdx.x;
    int lane = t & 63;
    int q = t >> 6;  // 0..3

    const float* xb = x + (size_t)b * C_IN * N_IN;
    int i = i0 + lane;
    if (i < N_IN) {
#pragma unroll
        for (int p = 0; p < 32; p++) {
            int k = p * 4 + q;
            tile[lane][k] = xb[(size_t)k * N_IN + i];
        }
    }
    __syncthreads();

    unsigned short* xTb = xT + (size_t)b * N_IN * C_IN;
#pragma unroll
    for (int p = 0; p < 16; p++) {
        int il = p * 4 + q;
        int gi = i0 + il;
        if (gi < N_IN) {
            int k2 = lane * 2;
            float a = tile[il][k2];
            float c = tile[il][k2 + 1];
            unsigned int pk = (unsigned int)f2bf(a) | ((unsigned int)f2bf(c) << 16);
            *reinterpret_cast<unsigned int*>(xTb + (size_t)gi * C_IN + k2) = pk;
        }
    }
}

// ---------------------------------------------------------------------------
// K2: fused gather-mean + GEMM (bf16 MFMA) + bias + y write + partial sums
//   y[b][o][n] = sum_k W[o][k] * g[b][k][n] + bias[o]
//   g[b][k][n] = mean_j xT[b][idx[7n+j]][k]
// Block: (b, 64-col n-tile). 4 waves, wave w owns channels [w*64, w*64+64).
// ---------------------------------------------------------------------------
#define NTILE 64
#define NB_N ((N_OUT + NTILE - 1) / NTILE)  // 161

__global__ __launch_bounds__(256) void k_gemm(const unsigned short* __restrict__ xT,
                                              const int* __restrict__ idx,
                                              const float* __restrict__ W,
                                              const float* __restrict__ bias,
                                              float* __restrict__ y,
                                              float* __restrict__ sums) {
    int b  = blockIdx.x / NB_N;
    int nb = blockIdx.x % NB_N;
    int n0 = nb * NTILE;
    int t = threadIdx.x;
    int w = t >> 6;       // wave 0..3
    int l = t & 63;
    int lr = l & 15;      // A-row / B-col / D-col within 16-tile
    int lg = l >> 4;      // k-chunk group / D-row group
    int wbase = w * 64;

    // A fragments from W (f32 global -> bf16 regs). Each block reads W once (L2-hot).
    bf16x8 afrag[4][4];   // [mt][ks]
#pragma unroll
    for (int mt = 0; mt < 4; mt++) {
        int o = wbase + mt * 16 + lr;
        const float* wr = W + (size_t)o * C_IN;
#pragma unroll
        for (int ks = 0; ks < 4; ks++) {
            int k0 = ks * 32 + lg * 8;
            f32x4 w0 = *reinterpret_cast<const f32x4*>(wr + k0);
            f32x4 w1 = *reinterpret_cast<const f32x4*>(wr + k0 + 4);
            bf16x8 f;
#pragma unroll
            for (int e = 0; e < 4; e++) {
                f[e]     = (short)f2bf(w0[e]);
                f[e + 4] = (short)f2bf(w1[e]);
            }
            afrag[mt][ks] = f;
        }
    }

    f32x4 acc[4][4];  // [mt][nt]
#pragma unroll
    for (int mt = 0; mt < 4; mt++)
#pragma unroll
        for (int nt = 0; nt < 4; nt++) acc[mt][nt] = (f32x4)(0.0f);

    const unsigned short* xTb = xT + (size_t)b * N_IN * C_IN;

#pragma unroll
    for (int nt = 0; nt < 4; nt++) {
        int n = n0 + nt * 16 + lr;
        int nc = (n < N_OUT) ? n : 0;
        int id[7];
#pragma unroll
        for (int j = 0; j < 7; j++) id[j] = idx[7 * nc + j];

#pragma unroll
        for (int ks = 0; ks < 4; ks++) {
            int k0 = ks * 32 + lg * 8;
            float s0 = 0.f, s1 = 0.f, s2 = 0.f, s3 = 0.f, s4 = 0.f, s5 = 0.f, s6 = 0.f, s7 = 0.f;
#pragma unroll
            for (int j = 0; j < 7; j++) {
                bf16x8 v = *reinterpret_cast<const bf16x8*>(xTb + (size_t)id[j] * C_IN + k0);
                s0 += bf2f((unsigned short)v[0]);
                s1 += bf2f((unsigned short)v[1]);
                s2 += bf2f((unsigned short)v[2]);
                s3 += bf2f((unsigned short)v[3]);
                s4 += bf2f((unsigned short)v[4]);
                s5 += bf2f((unsigned short)v[5]);
                s6 += bf2f((unsigned short)v[6]);
                s7 += bf2f((unsigned short)v[7]);
            }
            const float inv7 = 1.0f / 7.0f;
            bf16x8 bfr;
            bfr[0] = (short)f2bf(s0 * inv7);
            bfr[1] = (short)f2bf(s1 * inv7);
            bfr[2] = (short)f2bf(s2 * inv7);
            bfr[3] = (short)f2bf(s3 * inv7);
            bfr[4] = (short)f2bf(s4 * inv7);
            bfr[5] = (short)f2bf(s5 * inv7);
            bfr[6] = (short)f2bf(s6 * inv7);
            bfr[7] = (short)f2bf(s7 * inv7);
#pragma unroll
            for (int mt = 0; mt < 4; mt++)
                acc[mt][nt] = __builtin_amdgcn_mfma_f32_16x16x32_bf16(afrag[mt][ks], bfr,
                                                                     acc[mt][nt], 0, 0, 0);
        }
    }

    // Epilogue: bias, y write, per-channel partial sums
    float* yb = y + (size_t)b * C_OUT * N_OUT;
    float ps1[16], ps2[16];
#pragma unroll
    for (int m = 0; m < 16; m++) { ps1[m] = 0.f; ps2[m] = 0.f; }

#pragma unroll
    for (int mt = 0; mt < 4; mt++) {
#pragma unroll
        for (int j = 0; j < 4; j++) {
            int o = wbase + mt * 16 + lg * 4 + j;
            float bv = bias[o];
#pragma unroll
            for (int nt = 0; nt < 4; nt++) {
                int n = n0 + nt * 16 + lr;
                float v = acc[mt][nt][j] + bv;
                if (n < N_OUT) {
                    yb[(size_t)o * N_OUT + n] = v;
                    ps1[mt * 4 + j] += v;
                    ps2[mt * 4 + j] += v * v;
                }
            }
        }
    }

    // Reduce across the 16 lanes (lr) that share a channel, then one atomic each.
#pragma unroll
    for (int m = 0; m < 16; m++) {
        float a = ps1[m], c = ps2[m];
#pragma unroll
        for (int d = 1; d < 16; d <<= 1) {
            a += __shfl_xor(a, d, 64);
            c += __shfl_xor(c, d, 64);
        }
        if (lr == 0) {
            int mt = m >> 2, j = m & 3;
            int o = wbase + mt * 16 + lg * 4 + j;
            atomicAdd(&sums[o], a);
            atomicAdd(&sums[C_OUT + o], c);
        }
    }
}

// ---------------------------------------------------------------------------
// K3: finalize stats -> per-channel scale/shift
// ---------------------------------------------------------------------------
__global__ void k_stats(const float* __restrict__ sums, const float* __restrict__ gamma,
                        const float* __restrict__ beta, float* __restrict__ ss) {
    int o = threadIdx.x;
    const float cnt = (float)(B_ * N_OUT);
    float mean = sums[o] / cnt;
    float var = sums[C_OUT + o] / cnt - mean * mean;
    float rstd = rsqrtf(var + EPS_);
    float a = gamma[o] * rstd;
    ss[o] = a;
    ss[C_OUT + o] = beta[o] - mean * a;
}

// ---------------------------------------------------------------------------
// K4: in-place normalize: out = y*scale[o] + shift[o]. One row (b,o) per block.
// ---------------------------------------------------------------------------
__global__ __launch_bounds__(256) void k_norm(float* __restrict__ y, const float* __restrict__ ss) {
    int row = blockIdx.x;          // b*C_OUT + o
    int o = row & (C_OUT - 1);
    float a = ss[o];
    float c = ss[C_OUT + o];
    float* p = y + (size_t)row * N_OUT;
    f32x4* p4 = reinterpret_cast<f32x4*>(p);
    const int nv = N_OUT / 4;      // 2560
    for (int i = threadIdx.x; i < nv; i += 256) {
        f32x4 v = p4[i];
        v = v * a + c;
        p4[i] = v;
    }
    if (threadIdx.x < (N_OUT & 3)) {
        int i = (N_OUT & ~3) + threadIdx.x;
        p[i] = p[i] * a + c;
    }
}

// ---------------------------------------------------------------------------
extern "C" void kernel_launch(void* const* d_in, const int* in_sizes, int n_in,
                              void* d_out, int out_size, void* d_ws, size_t ws_size,
                              hipStream_t stream) {
    const float* x     = (const float*)d_in[0];
    const int*   idx   = (const int*)d_in[1];
    const float* W     = (const float*)d_in[2];
    const float* bias  = (const float*)d_in[3];
    const float* gamma = (const float*)d_in[4];
    const float* beta  = (const float*)d_in[5];
    float* out = (float*)d_out;

    const size_t xt_bytes = (size_t)B_ * N_IN * C_IN * sizeof(unsigned short);  // ~41.9 MB
    unsigned short* xT = (unsigned short*)d_ws;
    float* sums = (float*)((char*)d_ws + xt_bytes);   // 512 floats: [sum | sumsq]
    float* ss   = sums + 2 * C_OUT;                   // 512 floats: [scale | shift]

    hipMemsetAsync(sums, 0, 2 * C_OUT * sizeof(float), stream);
    k_transpose<<<B_ * NB_I, 256, 0, stream>>>(x, xT);
    k_gemm<<<B_ * NB_N, 256, 0, stream>>>(xT, idx, W, bias, out, sums);
    k_stats<<<1, C_OUT, 0, stream>>>(sums, gamma, beta, ss);
    k_norm<<<B_ * C_OUT, 256, 0, stream>>>(out, ss);
}